// Round 3
// baseline (778.546 us; speedup 1.0000x reference)
//
#include <hip/hip_runtime.h>
#include <math.h>

#define S_ 512
#define B_ 64
#define C_ 1024
#define T_ 128
#define V_ 10
#define LN_EPS 1e-5f

// ---------- Phase 1a: per (t,b): softmax(values@Wd.T+bd), sigmoid(values@Wr[1]+br[1])
// one wave per (t,b); stores float4 {d0,d1,d2,rw1} at dtr[(t*64+b)*4]
__global__ __launch_bounds__(256) void k_dirs(const float* __restrict__ values,
                                              const float* __restrict__ Wd,
                                              const float* __restrict__ bd,
                                              const float* __restrict__ Wr,
                                              const float* __restrict__ br,
                                              float* __restrict__ dtr) {
    int wid  = (blockIdx.x << 2) + (threadIdx.x >> 6);   // 0..32767 = t*64+b
    int lane = threadIdx.x & 63;
    const float4* v4  = (const float4*)(values + (size_t)wid * C_);
    const float4* wd4 = (const float4*)Wd;
    const float4* wr4 = (const float4*)Wr;
    float a0 = 0.f, a1 = 0.f, a2 = 0.f, a3 = 0.f;
#pragma unroll
    for (int k = 0; k < 4; k++) {
        int i = (k << 6) + lane;           // float4 index within 256
        float4 v  = v4[i];
        float4 w0 = wd4[i];
        float4 w1 = wd4[256 + i];
        float4 w2 = wd4[512 + i];
        float4 w3 = wr4[256 + i];          // Wr row 1
        a0 = fmaf(v.x, w0.x, fmaf(v.y, w0.y, fmaf(v.z, w0.z, fmaf(v.w, w0.w, a0))));
        a1 = fmaf(v.x, w1.x, fmaf(v.y, w1.y, fmaf(v.z, w1.z, fmaf(v.w, w1.w, a1))));
        a2 = fmaf(v.x, w2.x, fmaf(v.y, w2.y, fmaf(v.z, w2.z, fmaf(v.w, w2.w, a2))));
        a3 = fmaf(v.x, w3.x, fmaf(v.y, w3.y, fmaf(v.z, w3.z, fmaf(v.w, w3.w, a3))));
    }
#pragma unroll
    for (int m = 1; m < 64; m <<= 1) {
        a0 += __shfl_xor(a0, m, 64);
        a1 += __shfl_xor(a1, m, 64);
        a2 += __shfl_xor(a2, m, 64);
        a3 += __shfl_xor(a3, m, 64);
    }
    if (lane == 0) {
        float l0 = a0 + bd[0], l1 = a1 + bd[1], l2 = a2 + bd[2];
        float mx = fmaxf(fmaxf(l0, l1), l2);
        float e0 = __expf(l0 - mx), e1 = __expf(l1 - mx), e2 = __expf(l2 - mx);
        float inv = 1.f / (e0 + e1 + e2);
        float r = 1.f / (1.f + __expf(-(a3 + br[1])));
        ((float4*)dtr)[wid] = make_float4(e0 * inv, e1 * inv, e2 * inv, r);
    }
}

// ---------- Phase 1b: evolve pos per batch; store pos_t (pre-update) for all t.
// one wave per b; pos[l] split: lane holds l=lane (p0) and l=lane+64 (p1).
__global__ __launch_bounds__(64) void k_pos(const float* __restrict__ dtr,
                                            float* __restrict__ pos_all) {
    int b = blockIdx.x;
    int lane = threadIdx.x;
    const float4* dtr4 = (const float4*)dtr;
    float4 dreg[8];
#pragma unroll
    for (int k = 0; k < 8; k++)
        dreg[k] = dtr4[(((size_t)(k << 6) + lane) << 6) + b];   // t = k*64+lane
    float p0 = (lane == 0) ? 1.f : 0.f;
    float p1 = 0.f;
    float* outp = pos_all + ((size_t)b << 7) + lane;
    int up = (lane + 1) & 63, dw = (lane + 63) & 63;
#pragma unroll
    for (int k = 0; k < 8; k++) {
#pragma unroll 4
        for (int tt = 0; tt < 64; tt++) {
            int t = (k << 6) + tt;
            float d0 = __shfl(dreg[k].x, tt, 64);
            float d1 = __shfl(dreg[k].y, tt, 64);
            float d2 = __shfl(dreg[k].z, tt, 64);
            outp[(size_t)t * (B_ * T_)]      = p0;   // pos_t before update
            outp[(size_t)t * (B_ * T_) + 64] = p1;
            float s0n = __shfl(p0, up, 64), s1n = __shfl(p1, up, 64);
            float s0p = __shfl(p0, dw, 64), s1p = __shfl(p1, dw, 64);
            float up0 = (lane == 63) ? s1n : s0n;   // pos[(l+1)%128], l=lane
            float dn0 = (lane == 0)  ? s1p : s0p;   // pos[(l-1)%128]
            float up1 = (lane == 63) ? s0n : s1n;   // l=lane+64
            float dn1 = (lane == 0)  ? s0p : s1p;
            p0 = fmaf(up0, d0, fmaf(p0, d1, dn0 * d2));
            p1 = fmaf(up1, d0, fmaf(p1, d1, dn1 * d2));
        }
    }
}

// ---------- Phase 2: the scan, fused update+dot pass.
// Lane owns ONE c and an l-half (64 tape values in regs). Per step t, a single
// pass does: tape[l] += pos_t[l]*delta_t  (update for t), then immediately
// acc += pos_{t+1}[l]*tape[l]  (dot for t+1 on the updated tape). Cross-lane
// reduce is ONE shfl_xor(32) (two l-halves). pos_t stays register-resident
// (P/Q ping-pong, t-loop unrolled x2 so no register copies); only pos_{t+1}
// (16 float4, half-wave-uniform address) is loaded per step.
// Lanes: g = lane>>5 (l-half), cl = lane&31 (c). Wave covers 32 c.
// Grid: b(64) x cblk(8), 4 waves/block -> 512 blocks = 2 waves/SIMD.
__global__ __launch_bounds__(256, 2) void k_scan(const float* __restrict__ values,
                                                 const float* __restrict__ dtr,
                                                 const float* __restrict__ pos_all,
                                                 float* __restrict__ tape_out) {
    int b    = blockIdx.x >> 3;
    int cblk = blockIdx.x & 7;
    int lane = threadIdx.x & 63;
    int wv   = threadIdx.x >> 6;          // wave in block, 0..3
    int g    = lane >> 5;                 // l-half, 0..1 (l in [64g, 64g+64))
    int cl   = lane & 31;
    int c    = (cblk << 7) + (wv << 5) + cl;

    float4 tape[16];
#pragma unroll
    for (int j = 0; j < 16; j++) tape[j] = make_float4(0.f, 0.f, 0.f, 0.f);

    const float* vp = values + (size_t)b * C_ + c;
    const float* rp = dtr + (size_t)b * 4 + 3;

    // prologue: P = pos_0; delta_0 = v_0 * rw_0 (tape = 0 -> ov = 0)
    float4 P[16], Q[16];
    {
        const float4* pp0 = (const float4*)(pos_all + (size_t)b * T_) + (g << 4);
#pragma unroll
        for (int j = 0; j < 16; j++) P[j] = pp0[j];
    }
    float delta = vp[0] * rp[0];

#define FUSED_STEP(PC, PN, TT)                                                   \
    {                                                                            \
        const float4* pn_ = (const float4*)(pos_all +                            \
            ((size_t)((TT) + 1) * B_ + b) * T_) + (g << 4);                      \
        float vnext_ = vp[(size_t)((TT) + 1) * (B_ * C_)];                       \
        float rwn_   = rp[(size_t)((TT) + 1) * (B_ * 4)];                        \
        _Pragma("unroll")                                                        \
        for (int j = 0; j < 16; j++) PN[j] = pn_[j];                             \
        float a0 = 0.f, a1 = 0.f, a2 = 0.f, a3 = 0.f;                            \
        _Pragma("unroll")                                                        \
        for (int j = 0; j < 16; j++) {                                           \
            tape[j].x = fmaf(PC[j].x, delta, tape[j].x);                         \
            a0 = fmaf(PN[j].x, tape[j].x, a0);                                   \
            tape[j].y = fmaf(PC[j].y, delta, tape[j].y);                         \
            a1 = fmaf(PN[j].y, tape[j].y, a1);                                   \
            tape[j].z = fmaf(PC[j].z, delta, tape[j].z);                         \
            a2 = fmaf(PN[j].z, tape[j].z, a2);                                   \
            tape[j].w = fmaf(PC[j].w, delta, tape[j].w);                         \
            a3 = fmaf(PN[j].w, tape[j].w, a3);                                   \
        }                                                                        \
        float ov_ = (a0 + a1) + (a2 + a3);                                       \
        ov_ += __shfl_xor(ov_, 32, 64);                                          \
        delta = (vnext_ - ov_) * rwn_;                                           \
    }

    int t = 0;
    for (; t < S_ - 2; t += 2) {
        FUSED_STEP(P, Q, t)
        FUSED_STEP(Q, P, t + 1)
    }
    FUSED_STEP(P, Q, t)   // t = S_-2: loads pos_{S_-1} into Q, delta for S_-1

    // epilogue: final update with pos_{S_-1} (in Q) and delta_{S_-1}
#pragma unroll
    for (int j = 0; j < 16; j++) {
        tape[j].x = fmaf(Q[j].x, delta, tape[j].x);
        tape[j].y = fmaf(Q[j].y, delta, tape[j].y);
        tape[j].z = fmaf(Q[j].z, delta, tape[j].z);
        tape[j].w = fmaf(Q[j].w, delta, tape[j].w);
    }
#undef FUSED_STEP

    // writeout: layout [l][b][c]; this lane owns l = 64g + 4j+e, column c
    float* tp = tape_out + (size_t)b * C_ + c;
#pragma unroll
    for (int j = 0; j < 16; j++) {
        int l = (g << 6) + (j << 2);
        tp[(size_t)(l + 0) * (B_ * C_)] = tape[j].x;
        tp[(size_t)(l + 1) * (B_ * C_)] = tape[j].y;
        tp[(size_t)(l + 2) * (B_ * C_)] = tape[j].z;
        tp[(size_t)(l + 3) * (B_ * C_)] = tape[j].w;
    }
}

// ---------- Phase 3: LayerNorm over C + projection to V=10. one wave per (l,b).
__global__ __launch_bounds__(256) void k_out(const float* __restrict__ tape,
                                             const float* __restrict__ ln_g,
                                             const float* __restrict__ ln_b,
                                             const float* __restrict__ Wo,
                                             const float* __restrict__ bo,
                                             float* __restrict__ out) {
    int wid  = (blockIdx.x << 2) + (threadIdx.x >> 6);   // 0..8191 = l*64+b
    int lane = threadIdx.x & 63;
    const float* tr = tape + (size_t)wid * C_;
    float x[16];
    float s = 0.f, s2 = 0.f;
#pragma unroll
    for (int k = 0; k < 16; k++) {
        x[k] = tr[(k << 6) + lane];
        s += x[k];
        s2 = fmaf(x[k], x[k], s2);
    }
#pragma unroll
    for (int m = 1; m < 64; m <<= 1) {
        s  += __shfl_xor(s,  m, 64);
        s2 += __shfl_xor(s2, m, 64);
    }
    float mu = s * (1.f / C_);
    float var = s2 * (1.f / C_) - mu * mu;
    float rstd = rsqrtf(var + LN_EPS);
    float acc[V_];
#pragma unroll
    for (int v = 0; v < V_; v++) acc[v] = 0.f;
#pragma unroll
    for (int k = 0; k < 16; k++) {
        int cc = (k << 6) + lane;
        float h = fmaf((x[k] - mu) * rstd, ln_g[cc], ln_b[cc]);
#pragma unroll
        for (int v = 0; v < V_; v++) acc[v] = fmaf(h, Wo[v * C_ + cc], acc[v]);
    }
#pragma unroll
    for (int v = 0; v < V_; v++) {
#pragma unroll
        for (int m = 1; m < 64; m <<= 1) acc[v] += __shfl_xor(acc[v], m, 64);
    }
    if (lane == 0) {
#pragma unroll
        for (int v = 0; v < V_; v++) out[(size_t)wid * V_ + v] = acc[v] + bo[v];
    }
}

extern "C" void kernel_launch(void* const* d_in, const int* in_sizes, int n_in,
                              void* d_out, int out_size, void* d_ws, size_t ws_size,
                              hipStream_t stream) {
    const float* values = (const float*)d_in[0];
    const float* Wd     = (const float*)d_in[1];
    const float* bd     = (const float*)d_in[2];
    const float* Wr     = (const float*)d_in[3];
    const float* br     = (const float*)d_in[4];
    const float* ln_g   = (const float*)d_in[5];
    const float* ln_b   = (const float*)d_in[6];
    const float* Wo     = (const float*)d_in[7];
    const float* bo     = (const float*)d_in[8];
    float* out = (float*)d_out;

    // workspace layout (floats): dtr [512*64*4] | pos_all [512*64*128] | tape [128*64*1024]
    float* dtr     = (float*)d_ws;
    float* pos_all = dtr + (size_t)S_ * B_ * 4;
    float* tape    = pos_all + (size_t)S_ * B_ * T_;

    k_dirs<<<dim3((S_ * B_) / 4), dim3(256), 0, stream>>>(values, Wd, bd, Wr, br, dtr);
    k_pos <<<dim3(B_),            dim3(64),  0, stream>>>(dtr, pos_all);
    k_scan<<<dim3(B_ * 8),        dim3(256), 0, stream>>>(values, dtr, pos_all, tape);
    k_out <<<dim3((T_ * B_) / 4), dim3(256), 0, stream>>>(tape, ln_g, ln_b, Wo, bo, out);
}

// Round 4
// 535.166 us; speedup vs baseline: 1.4548x; 1.4548x over previous
//
#include <hip/hip_runtime.h>
#include <math.h>

#define S_ 512
#define B_ 64
#define C_ 1024
#define T_ 128
#define V_ 10
#define LN_EPS 1e-5f

// ---------- Phase 1a: per (t,b): softmax(values@Wd.T+bd), sigmoid(values@Wr[1]+br[1])
// one wave per (t,b); stores float4 {d0,d1,d2,rw1} at dtr[(t*64+b)*4]
__global__ __launch_bounds__(256) void k_dirs(const float* __restrict__ values,
                                              const float* __restrict__ Wd,
                                              const float* __restrict__ bd,
                                              const float* __restrict__ Wr,
                                              const float* __restrict__ br,
                                              float* __restrict__ dtr) {
    int wid  = (blockIdx.x << 2) + (threadIdx.x >> 6);   // 0..32767 = t*64+b
    int lane = threadIdx.x & 63;
    const float4* v4  = (const float4*)(values + (size_t)wid * C_);
    const float4* wd4 = (const float4*)Wd;
    const float4* wr4 = (const float4*)Wr;
    float a0 = 0.f, a1 = 0.f, a2 = 0.f, a3 = 0.f;
#pragma unroll
    for (int k = 0; k < 4; k++) {
        int i = (k << 6) + lane;           // float4 index within 256
        float4 v  = v4[i];
        float4 w0 = wd4[i];
        float4 w1 = wd4[256 + i];
        float4 w2 = wd4[512 + i];
        float4 w3 = wr4[256 + i];          // Wr row 1
        a0 = fmaf(v.x, w0.x, fmaf(v.y, w0.y, fmaf(v.z, w0.z, fmaf(v.w, w0.w, a0))));
        a1 = fmaf(v.x, w1.x, fmaf(v.y, w1.y, fmaf(v.z, w1.z, fmaf(v.w, w1.w, a1))));
        a2 = fmaf(v.x, w2.x, fmaf(v.y, w2.y, fmaf(v.z, w2.z, fmaf(v.w, w2.w, a2))));
        a3 = fmaf(v.x, w3.x, fmaf(v.y, w3.y, fmaf(v.z, w3.z, fmaf(v.w, w3.w, a3))));
    }
#pragma unroll
    for (int m = 1; m < 64; m <<= 1) {
        a0 += __shfl_xor(a0, m, 64);
        a1 += __shfl_xor(a1, m, 64);
        a2 += __shfl_xor(a2, m, 64);
        a3 += __shfl_xor(a3, m, 64);
    }
    if (lane == 0) {
        float l0 = a0 + bd[0], l1 = a1 + bd[1], l2 = a2 + bd[2];
        float mx = fmaxf(fmaxf(l0, l1), l2);
        float e0 = __expf(l0 - mx), e1 = __expf(l1 - mx), e2 = __expf(l2 - mx);
        float inv = 1.f / (e0 + e1 + e2);
        float r = 1.f / (1.f + __expf(-(a3 + br[1])));
        ((float4*)dtr)[wid] = make_float4(e0 * inv, e1 * inv, e2 * inv, r);
    }
}

// ---------- Phase 1b: evolve pos per batch; store pos_t (pre-update) for all t.
// one wave per b; pos[l] split: lane holds l=lane (p0) and l=lane+64 (p1).
__global__ __launch_bounds__(64) void k_pos(const float* __restrict__ dtr,
                                            float* __restrict__ pos_all) {
    int b = blockIdx.x;
    int lane = threadIdx.x;
    const float4* dtr4 = (const float4*)dtr;
    float4 dreg[8];
#pragma unroll
    for (int k = 0; k < 8; k++)
        dreg[k] = dtr4[(((size_t)(k << 6) + lane) << 6) + b];   // t = k*64+lane
    float p0 = (lane == 0) ? 1.f : 0.f;
    float p1 = 0.f;
    float* outp = pos_all + ((size_t)b << 7) + lane;
    int up = (lane + 1) & 63, dw = (lane + 63) & 63;
#pragma unroll
    for (int k = 0; k < 8; k++) {
#pragma unroll 4
        for (int tt = 0; tt < 64; tt++) {
            int t = (k << 6) + tt;
            float d0 = __shfl(dreg[k].x, tt, 64);
            float d1 = __shfl(dreg[k].y, tt, 64);
            float d2 = __shfl(dreg[k].z, tt, 64);
            outp[(size_t)t * (B_ * T_)]      = p0;   // pos_t before update
            outp[(size_t)t * (B_ * T_) + 64] = p1;
            float s0n = __shfl(p0, up, 64), s1n = __shfl(p1, up, 64);
            float s0p = __shfl(p0, dw, 64), s1p = __shfl(p1, dw, 64);
            float up0 = (lane == 63) ? s1n : s0n;   // pos[(l+1)%128], l=lane
            float dn0 = (lane == 0)  ? s1p : s0p;   // pos[(l-1)%128]
            float up1 = (lane == 63) ? s0n : s1n;   // l=lane+64
            float dn1 = (lane == 0)  ? s0p : s1p;
            p0 = fmaf(up0, d0, fmaf(p0, d1, dn0 * d2));
            p1 = fmaf(up1, d0, fmaf(p1, d1, dn1 * d2));
        }
    }
}

// ---------- Phase 2: the scan, LDS-staged chunks + 4 waves/SIMD.
// Round-1 dataflow (thread owns 16 l x 2 c, 3-round shfl reduce over g) with:
//  - pos/v/rw staged in LDS, double-buffered in chunks of 8 steps. LDS
//    same-address reads broadcast -> the 8-way lane duplication is free.
//  - pos rows stored g-interleaved (float4 idx = j*8 + g) so each
//    ds_read_b128 (8 unique float4s across lanes) spans all 32 banks.
//  - T14 async staging: global loads for chunk k+1 issued BEFORE computing
//    chunk k; ds_write + one barrier per 8 steps.
// Lanes: g = lane>>3 (16 l's), cl = lane&7 (2 c's). Wave covers 16 c.
// Grid: 64 b x 16 cblk = 1024 blocks = 4 blocks/CU = 4 waves/SIMD.
__global__ __launch_bounds__(256, 4) void k_scan(const float* __restrict__ values,
                                                 const float* __restrict__ dtr,
                                                 const float* __restrict__ pos_all,
                                                 float* __restrict__ tape_out) {
    const int b    = blockIdx.x >> 4;
    const int cblk = blockIdx.x & 15;
    const int tid  = threadIdx.x;
    const int lane = tid & 63;
    const int wv   = tid >> 6;            // wave in block, 0..3
    const int g    = lane >> 3;           // l-group, 0..7 (l in [16g,16g+16))
    const int cl   = lane & 7;
    const int c    = (cblk << 6) + (wv << 4) + (cl << 1);   // 2 consecutive c

    __shared__ float4 pos_s[2][8][32];    // [buf][t][permuted float4 of 128 l]
    __shared__ float2 v_s[2][8][32];      // [buf][t][32 float2 = block's 64 c]
    __shared__ float  rw_s[2][8];

    float tape[16][2];
#pragma unroll
    for (int k = 0; k < 16; k++) { tape[k][0] = 0.f; tape[k][1] = 0.f; }

    // staging roles: thread tid handles (t-local tl, item pi)
    const int tl = tid >> 5;              // 0..7
    const int pi = tid & 31;              // float4 idx (pos) / float2 idx (v)
    const int p_dst = ((pi & 3) << 3) + (pi >> 2);   // g-interleave permutation
    const float4* pos4 = (const float4*)pos_all;
    const float2* val2 = (const float2*)values;

    // ---- prologue: stage chunk 0
    {
        float4 p = pos4[((size_t)tl * B_ + b) * (T_ / 4) + pi];
        float2 v = val2[((size_t)tl * B_ + b) * (C_ / 2) + (cblk << 5) + pi];
        pos_s[0][tl][p_dst] = p;
        v_s[0][tl][pi] = v;
        if (tid < 8) rw_s[0][tid] = dtr[(((size_t)tid * B_ + b) << 2) + 3];
    }
    __syncthreads();

    int cur = 0;
    for (int ch = 0; ch < S_ / 8; ch++) {
        // ---- issue prefetch loads for chunk ch+1 (latency hides under compute)
        float4 pf_p = make_float4(0.f, 0.f, 0.f, 0.f);
        float2 pf_v = make_float2(0.f, 0.f);
        float  pf_r = 0.f;
        const int t0n = (ch + 1) << 3;
        const bool more = (ch + 1 < S_ / 8);
        if (more) {
            pf_p = pos4[((size_t)(t0n + tl) * B_ + b) * (T_ / 4) + pi];
            pf_v = val2[((size_t)(t0n + tl) * B_ + b) * (C_ / 2) + (cblk << 5) + pi];
            if (tid < 8) pf_r = dtr[(((size_t)(t0n + tid) * B_ + b) << 2) + 3];
        }
        // ---- compute 8 steps from buf cur
#pragma unroll
        for (int ts = 0; ts < 8; ts++) {
            float4 Pq0 = pos_s[cur][ts][g];          // k 0..3   (l = 16g+k)
            float4 Pq1 = pos_s[cur][ts][8 + g];      // k 4..7
            float4 Pq2 = pos_s[cur][ts][16 + g];     // k 8..11
            float4 Pq3 = pos_s[cur][ts][24 + g];     // k 12..15
            float2 vv  = v_s[cur][ts][(wv << 3) + cl];
            float  rw  = rw_s[cur][ts];
            float oa0 = 0.f, oa1 = 0.f, ob0 = 0.f, ob1 = 0.f;
            oa0 = fmaf(tape[0][0],  Pq0.x, oa0);  oa1 = fmaf(tape[0][1],  Pq0.x, oa1);
            ob0 = fmaf(tape[1][0],  Pq0.y, ob0);  ob1 = fmaf(tape[1][1],  Pq0.y, ob1);
            oa0 = fmaf(tape[2][0],  Pq0.z, oa0);  oa1 = fmaf(tape[2][1],  Pq0.z, oa1);
            ob0 = fmaf(tape[3][0],  Pq0.w, ob0);  ob1 = fmaf(tape[3][1],  Pq0.w, ob1);
            oa0 = fmaf(tape[4][0],  Pq1.x, oa0);  oa1 = fmaf(tape[4][1],  Pq1.x, oa1);
            ob0 = fmaf(tape[5][0],  Pq1.y, ob0);  ob1 = fmaf(tape[5][1],  Pq1.y, ob1);
            oa0 = fmaf(tape[6][0],  Pq1.z, oa0);  oa1 = fmaf(tape[6][1],  Pq1.z, oa1);
            ob0 = fmaf(tape[7][0],  Pq1.w, ob0);  ob1 = fmaf(tape[7][1],  Pq1.w, ob1);
            oa0 = fmaf(tape[8][0],  Pq2.x, oa0);  oa1 = fmaf(tape[8][1],  Pq2.x, oa1);
            ob0 = fmaf(tape[9][0],  Pq2.y, ob0);  ob1 = fmaf(tape[9][1],  Pq2.y, ob1);
            oa0 = fmaf(tape[10][0], Pq2.z, oa0);  oa1 = fmaf(tape[10][1], Pq2.z, oa1);
            ob0 = fmaf(tape[11][0], Pq2.w, ob0);  ob1 = fmaf(tape[11][1], Pq2.w, ob1);
            oa0 = fmaf(tape[12][0], Pq3.x, oa0);  oa1 = fmaf(tape[12][1], Pq3.x, oa1);
            ob0 = fmaf(tape[13][0], Pq3.y, ob0);  ob1 = fmaf(tape[13][1], Pq3.y, ob1);
            oa0 = fmaf(tape[14][0], Pq3.z, oa0);  oa1 = fmaf(tape[14][1], Pq3.z, oa1);
            ob0 = fmaf(tape[15][0], Pq3.w, ob0);  ob1 = fmaf(tape[15][1], Pq3.w, ob1);
            float ov0 = oa0 + ob0, ov1 = oa1 + ob1;
#pragma unroll
            for (int m = 8; m < 64; m <<= 1) {
                ov0 += __shfl_xor(ov0, m, 64);
                ov1 += __shfl_xor(ov1, m, 64);
            }
            float d0 = (vv.x - ov0) * rw;
            float d1 = (vv.y - ov1) * rw;
            tape[0][0]  = fmaf(Pq0.x, d0, tape[0][0]);   tape[0][1]  = fmaf(Pq0.x, d1, tape[0][1]);
            tape[1][0]  = fmaf(Pq0.y, d0, tape[1][0]);   tape[1][1]  = fmaf(Pq0.y, d1, tape[1][1]);
            tape[2][0]  = fmaf(Pq0.z, d0, tape[2][0]);   tape[2][1]  = fmaf(Pq0.z, d1, tape[2][1]);
            tape[3][0]  = fmaf(Pq0.w, d0, tape[3][0]);   tape[3][1]  = fmaf(Pq0.w, d1, tape[3][1]);
            tape[4][0]  = fmaf(Pq1.x, d0, tape[4][0]);   tape[4][1]  = fmaf(Pq1.x, d1, tape[4][1]);
            tape[5][0]  = fmaf(Pq1.y, d0, tape[5][0]);   tape[5][1]  = fmaf(Pq1.y, d1, tape[5][1]);
            tape[6][0]  = fmaf(Pq1.z, d0, tape[6][0]);   tape[6][1]  = fmaf(Pq1.z, d1, tape[6][1]);
            tape[7][0]  = fmaf(Pq1.w, d0, tape[7][0]);   tape[7][1]  = fmaf(Pq1.w, d1, tape[7][1]);
            tape[8][0]  = fmaf(Pq2.x, d0, tape[8][0]);   tape[8][1]  = fmaf(Pq2.x, d1, tape[8][1]);
            tape[9][0]  = fmaf(Pq2.y, d0, tape[9][0]);   tape[9][1]  = fmaf(Pq2.y, d1, tape[9][1]);
            tape[10][0] = fmaf(Pq2.z, d0, tape[10][0]);  tape[10][1] = fmaf(Pq2.z, d1, tape[10][1]);
            tape[11][0] = fmaf(Pq2.w, d0, tape[11][0]);  tape[11][1] = fmaf(Pq2.w, d1, tape[11][1]);
            tape[12][0] = fmaf(Pq3.x, d0, tape[12][0]);  tape[12][1] = fmaf(Pq3.x, d1, tape[12][1]);
            tape[13][0] = fmaf(Pq3.y, d0, tape[13][0]);  tape[13][1] = fmaf(Pq3.y, d1, tape[13][1]);
            tape[14][0] = fmaf(Pq3.z, d0, tape[14][0]);  tape[14][1] = fmaf(Pq3.z, d1, tape[14][1]);
            tape[15][0] = fmaf(Pq3.w, d0, tape[15][0]);  tape[15][1] = fmaf(Pq3.w, d1, tape[15][1]);
        }
        // ---- land prefetched data into the other buffer
        if (more) {
            int nxt = cur ^ 1;
            pos_s[nxt][tl][p_dst] = pf_p;
            v_s[nxt][tl][pi] = pf_v;
            if (tid < 8) rw_s[nxt][tid] = pf_r;
        }
        __syncthreads();
        cur ^= 1;
    }

    // writeout: layout [l][b][c]; this lane owns l = 16g + k, c-pair at c
    float2* tp = (float2*)(tape_out + (size_t)b * C_ + c);
#pragma unroll
    for (int k = 0; k < 16; k++) {
        int l = (g << 4) + k;
        tp[(size_t)l * (B_ * C_ / 2)] = make_float2(tape[k][0], tape[k][1]);
    }
}

// ---------- Phase 3: LayerNorm over C + projection to V=10. one wave per (l,b).
__global__ __launch_bounds__(256) void k_out(const float* __restrict__ tape,
                                             const float* __restrict__ ln_g,
                                             const float* __restrict__ ln_b,
                                             const float* __restrict__ Wo,
                                             const float* __restrict__ bo,
                                             float* __restrict__ out) {
    int wid  = (blockIdx.x << 2) + (threadIdx.x >> 6);   // 0..8191 = l*64+b
    int lane = threadIdx.x & 63;
    const float* tr = tape + (size_t)wid * C_;
    float x[16];
    float s = 0.f, s2 = 0.f;
#pragma unroll
    for (int k = 0; k < 16; k++) {
        x[k] = tr[(k << 6) + lane];
        s += x[k];
        s2 = fmaf(x[k], x[k], s2);
    }
#pragma unroll
    for (int m = 1; m < 64; m <<= 1) {
        s  += __shfl_xor(s,  m, 64);
        s2 += __shfl_xor(s2, m, 64);
    }
    float mu = s * (1.f / C_);
    float var = s2 * (1.f / C_) - mu * mu;
    float rstd = rsqrtf(var + LN_EPS);
    float acc[V_];
#pragma unroll
    for (int v = 0; v < V_; v++) acc[v] = 0.f;
#pragma unroll
    for (int k = 0; k < 16; k++) {
        int cc = (k << 6) + lane;
        float h = fmaf((x[k] - mu) * rstd, ln_g[cc], ln_b[cc]);
#pragma unroll
        for (int v = 0; v < V_; v++) acc[v] = fmaf(h, Wo[v * C_ + cc], acc[v]);
    }
#pragma unroll
    for (int v = 0; v < V_; v++) {
#pragma unroll
        for (int m = 1; m < 64; m <<= 1) acc[v] += __shfl_xor(acc[v], m, 64);
    }
    if (lane == 0) {
#pragma unroll
        for (int v = 0; v < V_; v++) out[(size_t)wid * V_ + v] = acc[v] + bo[v];
    }
}

extern "C" void kernel_launch(void* const* d_in, const int* in_sizes, int n_in,
                              void* d_out, int out_size, void* d_ws, size_t ws_size,
                              hipStream_t stream) {
    const float* values = (const float*)d_in[0];
    const float* Wd     = (const float*)d_in[1];
    const float* bd     = (const float*)d_in[2];
    const float* Wr     = (const float*)d_in[3];
    const float* br     = (const float*)d_in[4];
    const float* ln_g   = (const float*)d_in[5];
    const float* ln_b   = (const float*)d_in[6];
    const float* Wo     = (const float*)d_in[7];
    const float* bo     = (const float*)d_in[8];
    float* out = (float*)d_out;

    // workspace layout (floats): dtr [512*64*4] | pos_all [512*64*128] | tape [128*64*1024]
    float* dtr     = (float*)d_ws;
    float* pos_all = dtr + (size_t)S_ * B_ * 4;
    float* tape    = pos_all + (size_t)S_ * B_ * T_;

    k_dirs<<<dim3((S_ * B_) / 4), dim3(256), 0, stream>>>(values, Wd, bd, Wr, br, dtr);
    k_pos <<<dim3(B_),            dim3(64),  0, stream>>>(dtr, pos_all);
    k_scan<<<dim3(B_ * 16),       dim3(256), 0, stream>>>(values, dtr, pos_all, tape);
    k_out <<<dim3((T_ * B_) / 4), dim3(256), 0, stream>>>(tape, ln_g, ln_b, Wo, bo, out);
}

// Round 5
// 485.102 us; speedup vs baseline: 1.6049x; 1.1032x over previous
//
#include <hip/hip_runtime.h>
#include <math.h>

#define S_ 512
#define B_ 64
#define C_ 1024
#define T_ 128
#define V_ 10
#define LN_EPS 1e-5f

// DPP reduce-add helper: x += x permuted by CTRL (all lanes active).
// CTRL: 0xB1 = quad_perm[1,0,3,2] (xor1), 0x4E = quad_perm[2,3,0,1] (xor2),
//       0x141 = row_half_mirror (exchange 4-groups within 8 lanes).
#define DPP_ADD(x, ctrl)                                                     \
    ((x) + __int_as_float(__builtin_amdgcn_update_dpp(                       \
               0, __float_as_int(x), (ctrl), 0xf, 0xf, true)))

// ---------- Phase 1a: per (t,b): softmax(values@Wd.T+bd), sigmoid(values@Wr[1]+br[1])
__global__ __launch_bounds__(256) void k_dirs(const float* __restrict__ values,
                                              const float* __restrict__ Wd,
                                              const float* __restrict__ bd,
                                              const float* __restrict__ Wr,
                                              const float* __restrict__ br,
                                              float* __restrict__ dtr) {
    int wid  = (blockIdx.x << 2) + (threadIdx.x >> 6);   // 0..32767 = t*64+b
    int lane = threadIdx.x & 63;
    const float4* v4  = (const float4*)(values + (size_t)wid * C_);
    const float4* wd4 = (const float4*)Wd;
    const float4* wr4 = (const float4*)Wr;
    float a0 = 0.f, a1 = 0.f, a2 = 0.f, a3 = 0.f;
#pragma unroll
    for (int k = 0; k < 4; k++) {
        int i = (k << 6) + lane;           // float4 index within 256
        float4 v  = v4[i];
        float4 w0 = wd4[i];
        float4 w1 = wd4[256 + i];
        float4 w2 = wd4[512 + i];
        float4 w3 = wr4[256 + i];          // Wr row 1
        a0 = fmaf(v.x, w0.x, fmaf(v.y, w0.y, fmaf(v.z, w0.z, fmaf(v.w, w0.w, a0))));
        a1 = fmaf(v.x, w1.x, fmaf(v.y, w1.y, fmaf(v.z, w1.z, fmaf(v.w, w1.w, a1))));
        a2 = fmaf(v.x, w2.x, fmaf(v.y, w2.y, fmaf(v.z, w2.z, fmaf(v.w, w2.w, a2))));
        a3 = fmaf(v.x, w3.x, fmaf(v.y, w3.y, fmaf(v.z, w3.z, fmaf(v.w, w3.w, a3))));
    }
#pragma unroll
    for (int m = 1; m < 64; m <<= 1) {
        a0 += __shfl_xor(a0, m, 64);
        a1 += __shfl_xor(a1, m, 64);
        a2 += __shfl_xor(a2, m, 64);
        a3 += __shfl_xor(a3, m, 64);
    }
    if (lane == 0) {
        float l0 = a0 + bd[0], l1 = a1 + bd[1], l2 = a2 + bd[2];
        float mx = fmaxf(fmaxf(l0, l1), l2);
        float e0 = __expf(l0 - mx), e1 = __expf(l1 - mx), e2 = __expf(l2 - mx);
        float inv = 1.f / (e0 + e1 + e2);
        float r = 1.f / (1.f + __expf(-(a3 + br[1])));
        ((float4*)dtr)[wid] = make_float4(e0 * inv, e1 * inv, e2 * inv, r);
    }
}

// ---------- Phase 1b: evolve pos per batch; store pos_t (pre-update) for all t.
__global__ __launch_bounds__(64) void k_pos(const float* __restrict__ dtr,
                                            float* __restrict__ pos_all) {
    int b = blockIdx.x;
    int lane = threadIdx.x;
    const float4* dtr4 = (const float4*)dtr;
    float4 dreg[8];
#pragma unroll
    for (int k = 0; k < 8; k++)
        dreg[k] = dtr4[(((size_t)(k << 6) + lane) << 6) + b];   // t = k*64+lane
    float p0 = (lane == 0) ? 1.f : 0.f;
    float p1 = 0.f;
    float* outp = pos_all + ((size_t)b << 7) + lane;
    int up = (lane + 1) & 63, dw = (lane + 63) & 63;
#pragma unroll
    for (int k = 0; k < 8; k++) {
#pragma unroll 4
        for (int tt = 0; tt < 64; tt++) {
            int t = (k << 6) + tt;
            float d0 = __shfl(dreg[k].x, tt, 64);
            float d1 = __shfl(dreg[k].y, tt, 64);
            float d2 = __shfl(dreg[k].z, tt, 64);
            outp[(size_t)t * (B_ * T_)]      = p0;   // pos_t before update
            outp[(size_t)t * (B_ * T_) + 64] = p1;
            float s0n = __shfl(p0, up, 64), s1n = __shfl(p1, up, 64);
            float s0p = __shfl(p0, dw, 64), s1p = __shfl(p1, dw, 64);
            float up0 = (lane == 63) ? s1n : s0n;   // pos[(l+1)%128], l=lane
            float dn0 = (lane == 0)  ? s1p : s0p;   // pos[(l-1)%128]
            float up1 = (lane == 63) ? s0n : s1n;   // l=lane+64
            float dn1 = (lane == 0)  ? s0p : s1p;
            p0 = fmaf(up0, d0, fmaf(p0, d1, dn0 * d2));
            p1 = fmaf(up1, d0, fmaf(p1, d1, dn1 * d2));
        }
    }
}

// ---------- Phase 2: the scan. LDS holds POS ONLY; v prefetched to regs;
// rw via scalar loads; l-group reduce via DPP (no LDS pipe).
// Lanes: g = lane&7 (16 l's: [16g,16g+16)), cl = lane>>3 (4 c's).
// Thread = 16 l x 4 c -> tape[16][4] in regs. Wave covers 32 c.
// Reduce over g = xor1/xor2/xor4 within 8 lanes = quad_perm, quad_perm,
// row_half_mirror DPP adds (pure VALU).
// pos LDS: slot p(pi) = (pi&3)*8 + (pi>>2); step read [ts][j*8+g] j=0..3
// -> 8 consecutive float4 slots per instr, all 32 banks, broadcast x8.
// Grid: 64 b x 8 cblk = 512 blocks = 2 blocks/CU = 2 waves/SIMD (VGPR<=256).
__global__ __launch_bounds__(256, 2) void k_scan(const float* __restrict__ values,
                                                 const float* __restrict__ dtr,
                                                 const float* __restrict__ pos_all,
                                                 float* __restrict__ tape_out) {
    const int b    = blockIdx.x >> 3;
    const int cblk = blockIdx.x & 7;
    const int tid  = threadIdx.x;
    const int lane = tid & 63;
    const int wv   = tid >> 6;            // wave in block, 0..3
    const int g    = lane & 7;            // l-group
    const int cl   = lane >> 3;           // c-slot in wave, 0..7
    const int c0   = (cblk << 7) + (wv << 5) + (cl << 2);   // 4 consecutive c

    __shared__ float4 pos_s[2][8][32];    // [buf][t][permuted float4 of 128 l]

    float tape[16][4];
#pragma unroll
    for (int k = 0; k < 16; k++)
#pragma unroll
        for (int c = 0; c < 4; c++) tape[k][c] = 0.f;

    // staging role: thread stages one float4 of pos per chunk
    const int tl  = tid >> 5;             // 0..7 (t within chunk)
    const int pi  = tid & 31;             // source float4 index
    const int pdst = ((pi & 3) << 3) + (pi >> 2);   // interleave permutation
    const float4* pos4 = (const float4*)pos_all;
    const float4* val4 = (const float4*)values;
    const size_t vidx0 = (size_t)b * (C_ / 4) + (c0 >> 2);

    // ---- prologue: stage chunk 0 (pos -> LDS, v/rw -> regs)
    float4 vcur[8];
    float  rwcur[8];
    {
        pos_s[0][tl][pdst] = pos4[((size_t)tl * B_ + b) * (T_ / 4) + pi];
#pragma unroll
        for (int i = 0; i < 8; i++) {
            vcur[i]  = val4[(size_t)i * (B_ * C_ / 4) + vidx0];
            rwcur[i] = dtr[(((size_t)i * B_ + b) << 2) + 3];
        }
    }
    __syncthreads();

    int cur = 0;
    for (int ch = 0; ch < S_ / 8; ch++) {
        // ---- prefetch chunk ch+1 (clamped re-read on the last chunk)
        const int t0n = (ch + 1 < S_ / 8) ? ((ch + 1) << 3) : 0;
        float4 pfp = pos4[((size_t)(t0n + tl) * B_ + b) * (T_ / 4) + pi];
        float4 vpf[8];
        float  rpf[8];
#pragma unroll
        for (int i = 0; i < 8; i++) {
            vpf[i] = val4[(size_t)(t0n + i) * (B_ * C_ / 4) + vidx0];
            rpf[i] = dtr[(((size_t)(t0n + i) * B_ + b) << 2) + 3];
        }
        // ---- compute 8 steps from buf cur
#pragma unroll
        for (int ts = 0; ts < 8; ts++) {
            float4 pj0 = pos_s[cur][ts][g];          // k 0..3   (l = 16g+k)
            float4 pj1 = pos_s[cur][ts][8 + g];      // k 4..7
            float4 pj2 = pos_s[cur][ts][16 + g];     // k 8..11
            float4 pj3 = pos_s[cur][ts][24 + g];     // k 12..15
            float pk[16];
            pk[0]  = pj0.x; pk[1]  = pj0.y; pk[2]  = pj0.z; pk[3]  = pj0.w;
            pk[4]  = pj1.x; pk[5]  = pj1.y; pk[6]  = pj1.z; pk[7]  = pj1.w;
            pk[8]  = pj2.x; pk[9]  = pj2.y; pk[10] = pj2.z; pk[11] = pj2.w;
            pk[12] = pj3.x; pk[13] = pj3.y; pk[14] = pj3.z; pk[15] = pj3.w;

            float ov[4] = {0.f, 0.f, 0.f, 0.f};
#pragma unroll
            for (int k = 0; k < 16; k++) {
                ov[0] = fmaf(tape[k][0], pk[k], ov[0]);
                ov[1] = fmaf(tape[k][1], pk[k], ov[1]);
                ov[2] = fmaf(tape[k][2], pk[k], ov[2]);
                ov[3] = fmaf(tape[k][3], pk[k], ov[3]);
            }
            // DPP reduce over the 8 l-groups (lane bits 0..2), pure VALU
#pragma unroll
            for (int c = 0; c < 4; c++) {
                ov[c] = DPP_ADD(ov[c], 0xB1);    // += lane^1
                ov[c] = DPP_ADD(ov[c], 0x4E);    // += lane^2
                ov[c] = DPP_ADD(ov[c], 0x141);   // += lane^4 (half-mirror)
            }
            float rw = rwcur[ts];
            float de[4];
            de[0] = (vcur[ts].x - ov[0]) * rw;
            de[1] = (vcur[ts].y - ov[1]) * rw;
            de[2] = (vcur[ts].z - ov[2]) * rw;
            de[3] = (vcur[ts].w - ov[3]) * rw;
#pragma unroll
            for (int k = 0; k < 16; k++) {
                tape[k][0] = fmaf(pk[k], de[0], tape[k][0]);
                tape[k][1] = fmaf(pk[k], de[1], tape[k][1]);
                tape[k][2] = fmaf(pk[k], de[2], tape[k][2]);
                tape[k][3] = fmaf(pk[k], de[3], tape[k][3]);
            }
        }
        // ---- land prefetched pos into the other buffer; roll v/rw regs
        int nxt = cur ^ 1;
        pos_s[nxt][tl][pdst] = pfp;
#pragma unroll
        for (int i = 0; i < 8; i++) { vcur[i] = vpf[i]; rwcur[i] = rpf[i]; }
        __syncthreads();
        cur = nxt;
    }

    // writeout: layout [l][b][c]; this lane owns l = 16g + k, c = c0..c0+3
#pragma unroll
    for (int k = 0; k < 16; k++) {
        int l = (g << 4) + k;
        *(float4*)(tape_out + ((size_t)l * B_ + b) * C_ + c0) =
            make_float4(tape[k][0], tape[k][1], tape[k][2], tape[k][3]);
    }
}

// ---------- Phase 3: LayerNorm over C + projection to V=10. one wave per (l,b).
__global__ __launch_bounds__(256) void k_out(const float* __restrict__ tape,
                                             const float* __restrict__ ln_g,
                                             const float* __restrict__ ln_b,
                                             const float* __restrict__ Wo,
                                             const float* __restrict__ bo,
                                             float* __restrict__ out) {
    int wid  = (blockIdx.x << 2) + (threadIdx.x >> 6);   // 0..8191 = l*64+b
    int lane = threadIdx.x & 63;
    const float* tr = tape + (size_t)wid * C_;
    float x[16];
    float s = 0.f, s2 = 0.f;
#pragma unroll
    for (int k = 0; k < 16; k++) {
        x[k] = tr[(k << 6) + lane];
        s += x[k];
        s2 = fmaf(x[k], x[k], s2);
    }
#pragma unroll
    for (int m = 1; m < 64; m <<= 1) {
        s  += __shfl_xor(s,  m, 64);
        s2 += __shfl_xor(s2, m, 64);
    }
    float mu = s * (1.f / C_);
    float var = s2 * (1.f / C_) - mu * mu;
    float rstd = rsqrtf(var + LN_EPS);
    float acc[V_];
#pragma unroll
    for (int v = 0; v < V_; v++) acc[v] = 0.f;
#pragma unroll
    for (int k = 0; k < 16; k++) {
        int cc = (k << 6) + lane;
        float h = fmaf((x[k] - mu) * rstd, ln_g[cc], ln_b[cc]);
#pragma unroll
        for (int v = 0; v < V_; v++) acc[v] = fmaf(h, Wo[v * C_ + cc], acc[v]);
    }
#pragma unroll
    for (int v = 0; v < V_; v++) {
#pragma unroll
        for (int m = 1; m < 64; m <<= 1) acc[v] += __shfl_xor(acc[v], m, 64);
    }
    if (lane == 0) {
#pragma unroll
        for (int v = 0; v < V_; v++) out[(size_t)wid * V_ + v] = acc[v] + bo[v];
    }
}

extern "C" void kernel_launch(void* const* d_in, const int* in_sizes, int n_in,
                              void* d_out, int out_size, void* d_ws, size_t ws_size,
                              hipStream_t stream) {
    const float* values = (const float*)d_in[0];
    const float* Wd     = (const float*)d_in[1];
    const float* bd     = (const float*)d_in[2];
    const float* Wr     = (const float*)d_in[3];
    const float* br     = (const float*)d_in[4];
    const float* ln_g   = (const float*)d_in[5];
    const float* ln_b   = (const float*)d_in[6];
    const float* Wo     = (const float*)d_in[7];
    const float* bo     = (const float*)d_in[8];
    float* out = (float*)d_out;

    // workspace layout (floats): dtr [512*64*4] | pos_all [512*64*128] | tape [128*64*1024]
    float* dtr     = (float*)d_ws;
    float* pos_all = dtr + (size_t)S_ * B_ * 4;
    float* tape    = pos_all + (size_t)S_ * B_ * T_;

    k_dirs<<<dim3((S_ * B_) / 4), dim3(256), 0, stream>>>(values, Wd, bd, Wr, br, dtr);
    k_pos <<<dim3(B_),            dim3(64),  0, stream>>>(dtr, pos_all);
    k_scan<<<dim3(B_ * 8),        dim3(256), 0, stream>>>(values, dtr, pos_all, tape);
    k_out <<<dim3((T_ * B_) / 4), dim3(256), 0, stream>>>(tape, ln_g, ln_b, Wo, bo, out);
}